// Round 2
// baseline (334.821 us; speedup 1.0000x reference)
//
#include <hip/hip_runtime.h>

#define NEG (-10000.0f)
#define START_TAG 62
#define STOP_TAG 63
#define SLEN 512
#define BATCH 512
#define NTAG 64

// One wave per TWO batches; lane j = tag j.
//
// Round-6 change: ring-8 prefetch (round 5) was a -7% wash -> the stall is NOT
// feats load latency (depth-2 already had ~1870 cyc slack vs ~900 cyc HBM
// latency). Revised model: wave busy ~55%, remainder is distributed small
// latencies on a fully serial chain (16-deep FMA dep chains, v_exp/v_log
// latency, readlane->SGPR hazards, ds latency) with 1 wave/SIMD -> nothing to
// overlap with. Fix: TWO independent recursions per wave (grid 256). Batch A's
// dep stalls are issue slots for batch B. Per-batch math is kept bit-identical
// (same 4-chain summation order as the verified kernel). Mask columns for the
// pair live in LDS as float2 (one ds_read_b64 per step).
//
// Scaled linear-space recursion: p_i = exp(alpha_i - C), acc_j = sum_i p_i*E_ij,
// alpha'_j = C + log(acc_j) + f_j. C cancels exactly -> C = readfirstlane(alpha).
__global__ __launch_bounds__(64) __attribute__((amdgpu_waves_per_eu(1, 1)))
void crf_fwd(const float* __restrict__ feats,
             const int* __restrict__ tags,
             const float* __restrict__ mask,
             const float* __restrict__ trans,
             float* __restrict__ diff /* [BATCH] */) {
    const int bp = blockIdx.x;       // batch-pair id 0..255
    const int bA = 2 * bp;
    const int bB = 2 * bp + 1;
    const int j = threadIdx.x;       // tag lane 0..63

    __shared__ float2 smask[SLEN];   // 4 KB: mask columns for both batches

    // ---- E column in registers + column sum (for exact analytic step 0) ----
    float e[NTAG];
    float colsum = 0.0f;
#pragma unroll
    for (int i = 0; i < NTAG; ++i) {
        e[i] = __expf(trans[i * NTAG + j]); // exp(NEG) underflows to 0 - desired
        colsum += e[i];
    }
    const float tstop = trans[STOP_TAG * NTAG + j];

    // ---- mask column preload: lane j holds mask[(64k+j)*B + b], k=0..7 ----
    float mra[8], mrb[8];
#pragma unroll
    for (int k = 0; k < 8; ++k) {
        mra[k] = mask[(64 * k + j) * BATCH + bA];
        mrb[k] = mask[(64 * k + j) * BATCH + bB];
    }

    // stage both mask columns to LDS for uniform broadcast reads in the loop
#pragma unroll
    for (int k = 0; k < 8; ++k)
        smask[64 * k + j] = make_float2(mra[k], mrb[k]);

    // ---- step 0 (exact analytic; trans[START,:]==NEG) ----
    float fA0 = feats[(0 * BATCH + bA) * NTAG + j];
    float fB0 = feats[(0 * BATCH + bB) * NTAG + j];
    float m0A = __uint_as_float(__builtin_amdgcn_readlane(__float_as_uint(mra[0]), 0));
    float m0B = __uint_as_float(__builtin_amdgcn_readlane(__float_as_uint(mrb[0]), 0));
    float init_cold = (j == START_TAG) ? 0.0f : NEG;
    float alphaA = (m0A > 0.0f) ? (NEG + log1pf(colsum) + fA0) : init_cold;
    float alphaB = (m0B > 0.0f) ? (NEG + log1pf(colsum) + fB0) : init_cold;

    // force the s=0 loop iteration to be a no-op (alpha already holds step 0)
    if (j == 0) smask[0] = make_float2(0.0f, 0.0f);
    __syncthreads(); // 1 wave: cheap; orders ds_writes before loop ds_reads

    // ---- feats ring prefetch, depth 8 per batch (only vmcnt loads in loop) --
    const float* fpA = feats + (size_t)bA * NTAG + j;
    const float* fpB = feats + (size_t)bB * NTAG + j;
    float frA[8], frB[8];
#pragma unroll
    for (int t = 0; t < 8; ++t) {
        frA[t] = fpA[(size_t)t * BATCH * NTAG];
        frB[t] = fpB[(size_t)t * BATCH * NTAG];
    }

    for (int blk = 0; blk < 64; ++blk) {
#pragma unroll
        for (int t = 0; t < 8; ++t) {
            const int s = blk * 8 + t;
            const float fcA = frA[t];
            const float fcB = frB[t];
            int sp = s + 8;
            if (sp > SLEN - 1) sp = SLEN - 1; // tail: clamped garbage, never consumed
            frA[t] = fpA[(size_t)sp * BATCH * NTAG];
            frB[t] = fpB[(size_t)sp * BATCH * NTAG];

            // wave-uniform mask pair broadcast from LDS (in-order lgkmcnt)
            const float2 mk2 = smask[s];

            // scaling constants: lane 0's alpha (cancels exactly)
            float CA = __uint_as_float(
                __builtin_amdgcn_readfirstlane(__float_as_uint(alphaA)));
            float CB = __uint_as_float(
                __builtin_amdgcn_readfirstlane(__float_as_uint(alphaB)));
            float pA = __expf(alphaA - CA);
            float pB = __expf(alphaB - CB);

            // acc_j = sum_i p_i * E[i][j]; readlane broadcast, 4 chains/batch,
            // two independent batches interleaved -> dep stalls overlap
            unsigned puA = __float_as_uint(pA);
            unsigned puB = __float_as_uint(pB);
            float a0 = 0.0f, a1 = 0.0f, a2 = 0.0f, a3 = 0.0f;
            float b0 = 0.0f, b1 = 0.0f, b2 = 0.0f, b3 = 0.0f;
#pragma unroll
            for (int i = 0; i < NTAG; i += 4) {
                a0 = fmaf(__uint_as_float(__builtin_amdgcn_readlane(puA, i + 0)), e[i + 0], a0);
                b0 = fmaf(__uint_as_float(__builtin_amdgcn_readlane(puB, i + 0)), e[i + 0], b0);
                a1 = fmaf(__uint_as_float(__builtin_amdgcn_readlane(puA, i + 1)), e[i + 1], a1);
                b1 = fmaf(__uint_as_float(__builtin_amdgcn_readlane(puB, i + 1)), e[i + 1], b1);
                a2 = fmaf(__uint_as_float(__builtin_amdgcn_readlane(puA, i + 2)), e[i + 2], a2);
                b2 = fmaf(__uint_as_float(__builtin_amdgcn_readlane(puB, i + 2)), e[i + 2], b2);
                a3 = fmaf(__uint_as_float(__builtin_amdgcn_readlane(puA, i + 3)), e[i + 3], a3);
                b3 = fmaf(__uint_as_float(__builtin_amdgcn_readlane(puB, i + 3)), e[i + 3], b3);
            }
            float accA = (a0 + a1) + (a2 + a3);
            float accB = (b0 + b1) + (b2 + b3);

            float nxtA = CA + __logf(accA) + fcA; // acc==0 (STOP col) -> -inf, benign
            float nxtB = CB + __logf(accB) + fcB;
            alphaA = (mk2.x > 0.0f) ? nxtA : alphaA;
            alphaB = (mk2.y > 0.0f) ? nxtB : alphaB;
        }
    }

    // ---- epilogue 1: log_z = logsumexp_j(alpha_j + trans[STOP][j]) ----
    float logzAB[2];
#pragma unroll
    for (int bb = 0; bb < 2; ++bb) {
        float v = ((bb == 0) ? alphaA : alphaB) + tstop;
        float m2 = v;
#pragma unroll
        for (int w = 32; w >= 1; w >>= 1)
            m2 = fmaxf(m2, __shfl_xor(m2, w, 64));
        float pe = __expf(v - m2);
#pragma unroll
        for (int w = 32; w >= 1; w >>= 1)
            pe += __shfl_xor(pe, w, 64);
        logzAB[bb] = m2 + __logf(pe);
    }

    // ---- epilogue 2: true-path score; lanes parallel over time steps ----
#pragma unroll
    for (int bb = 0; bb < 2; ++bb) {
        const int bcur = 2 * bp + bb;
        float psc = 0.0f, pms = 0.0f;
#pragma unroll
        for (int k = 0; k < 8; ++k) {
            int s = j + 64 * k;
            int tg = tags[s * BATCH + bcur];
            float mk = (bb == 0) ? mra[k] : mrb[k]; // preloaded mask[s] for bcur
            int tprev = (s == 0) ? START_TAG : tags[(s - 1) * BATCH + bcur];
            float em = feats[((size_t)s * BATCH + bcur) * NTAG + tg];
            psc = fmaf(em + trans[tprev * NTAG + tg], mk, psc);
            pms += mk;
        }
#pragma unroll
        for (int w = 32; w >= 1; w >>= 1) {
            psc += __shfl_xor(psc, w, 64);
            pms += __shfl_xor(pms, w, 64);
        }
        if (j == 0) {
            int last_idx = (int)(pms + 0.5f) - 1;
            int ltag = tags[last_idx * BATCH + bcur];
            float score = psc + trans[ltag * NTAG + STOP_TAG];
            diff[bcur] = logzAB[bb] - score;
        }
    }
}

__global__ __launch_bounds__(512) void crf_reduce(const float* __restrict__ diff,
                                                  float* __restrict__ out) {
    __shared__ float sdata[8];
    int t = threadIdx.x;
    float val = diff[t];
#pragma unroll
    for (int w = 32; w >= 1; w >>= 1)
        val += __shfl_xor(val, w, 64);
    if ((t & 63) == 0) sdata[t >> 6] = val;
    __syncthreads();
    if (t == 0) {
        float ssum = 0.0f;
        for (int i = 0; i < 8; ++i) ssum += sdata[i];
        out[0] = ssum * (1.0f / (float)BATCH);
    }
}

extern "C" void kernel_launch(void* const* d_in, const int* in_sizes, int n_in,
                              void* d_out, int out_size, void* d_ws, size_t ws_size,
                              hipStream_t stream) {
    const float* feats = (const float*)d_in[0];
    const int* tags = (const int*)d_in[1];
    const float* mask = (const float*)d_in[2];
    const float* trans = (const float*)d_in[3];
    float* out = (float*)d_out;
    float* diff = (float*)d_ws; // 512 floats

    crf_fwd<<<BATCH / 2, 64, 0, stream>>>(feats, tags, mask, trans, diff);
    crf_reduce<<<1, 512, 0, stream>>>(diff, out);
}

// Round 3
// 198.963 us; speedup vs baseline: 1.6828x; 1.6828x over previous
//
#include <hip/hip_runtime.h>

#define NEG (-10000.0f)
#define START_TAG 62
#define STOP_TAG 63
#define SLEN 512
#define BATCH 512
#define NTAG 64

typedef float f32x2 __attribute__((ext_vector_type(2)));
typedef float f32x4 __attribute__((ext_vector_type(4)));

__device__ __forceinline__ float readlane_f(float v, int lane) {
    return __uint_as_float(__builtin_amdgcn_readlane(__float_as_uint(v), lane));
}

// One wave per batch; lane j = tag j.
//
// Round-7 redesign: rounds 5/6 falsified "hideable latency" (deep prefetch: no
// effect; 2-batch interleave: only ~20% overlap). Dominant cost attributed to
// the 64x (v_readlane -> SGPR -> v_fma) hazard pairs (~8-9 cyc each ~= the
// 872-300 cyc/step gap) plus the per-step exp/log roundtrip on the serial
// chain. Fix: full scaled EXP-SPACE recursion q_j = exp(alpha_j - A):
//   acc_j = sum_i q_i * E_ij     (E in VGPRs as f32x2 pairs, v_pk_fma_f32)
//   q'_j  = acc_j * exp(f_j) * rinv,   rinv = 2^-k EXACT from last step's
//           acc[lane0] exponent bits (readfirstlane+SALU, off-chain, 1/step)
//   A accumulates k*ln2 in an integer; logz = log(sum q*e^tstop) + C0 + ktot*ln2.
// Broadcast via LDS ping-pong (write q once, 16 uniform ds_read_b128 =
// broadcast, in-order DS pipe, no barrier needed in a single wave) -> zero
// readlane hazards, no exp/log on the chain (exp(f) precomputed off ring).
__global__ __launch_bounds__(64) __attribute__((amdgpu_waves_per_eu(1, 1)))
void crf_fwd(const float* __restrict__ feats,
             const int* __restrict__ tags,
             const float* __restrict__ mask,
             const float* __restrict__ trans,
             float* __restrict__ diff /* [BATCH] */) {
    const int b = blockIdx.x;
    const int j = threadIdx.x; // tag lane 0..63

    __shared__ float smask[SLEN];                 // wave-uniform mask column
    __shared__ __align__(16) float qraw[2][NTAG]; // q ping-pong, 2x256B

    // ---- E pairs in registers: e2[r] = (exp(T[2r][j]), exp(T[2r+1][j])) ----
    f32x2 e2[32];
    float colsum = 0.0f;
#pragma unroll
    for (int r = 0; r < 32; ++r) {
        float lo = __expf(trans[(2 * r) * NTAG + j]);     // exp(NEG) -> 0, desired
        float hi = __expf(trans[(2 * r + 1) * NTAG + j]);
        e2[r] = (f32x2){lo, hi};
        colsum += lo + hi;
    }
    const float tstop = trans[STOP_TAG * NTAG + j];

    // ---- mask column preload (also reused by epilogue 2) ----
    float mreg[8];
#pragma unroll
    for (int k = 0; k < 8; ++k) mreg[k] = mask[(64 * k + j) * BATCH + b];
#pragma unroll
    for (int k = 0; k < 8; ++k) smask[64 * k + j] = mreg[k];

    // ---- step 0 (exact analytic; trans[START,:]==NEG) ----
    float f_s0 = feats[(0 * BATCH + b) * NTAG + j];
    float m0 = readlane_f(mreg[0], 0);
    float alpha0 = (m0 > 0.0f) ? (NEG + log1pf(colsum) + f_s0)
                               : ((j == START_TAG) ? 0.0f : NEG);
    // C0 from lane START_TAG: valid in both warm (finite) and cold (max=0) cases
    const float C0 = readlane_f(alpha0, START_TAG);
    float q = __expf(alpha0 - C0); // cold: exp(NEG)->0 except START lane = 1

    if (j == 0) smask[0] = 0.0f; // s=0 loop iteration is a masked no-op
    qraw[0][j] = q;
    __syncthreads(); // single wave: cheap; orders LDS init before loop reads

    // ---- feats ring prefetch depth 8 (only vmcnt loads in the loop) ----
    const float* fp = feats + (size_t)b * NTAG + j;
    float fr[8];
#pragma unroll
    for (int t = 0; t < 8; ++t) fr[t] = fp[(size_t)t * BATCH * NTAG];

    float rinv = 1.0f; // wave-uniform pending normalizer 2^-kcur
    int kcur = 0;      // exponent embedded in rinv
    int ktot = 0;      // sum of APPLIED exponents

    for (int blk = 0; blk < 64; ++blk) {
#pragma unroll
        for (int t = 0; t < 8; ++t) {
            const int s = blk * 8 + t;
            const int ph = t & 1; // step parity == t parity (blk*8 even)

            const float mk = smask[s]; // uniform ds_read_b32

            float ef = __expf(fr[t]); // exp(feats[s]) - operand loaded 8 steps ago
            int sp = s + 8;
            if (sp > SLEN - 1) sp = SLEN - 1; // tail garbage, never consumed
            fr[t] = fp[(size_t)sp * BATCH * NTAG];
            float efr = ef * rinv; // off-chain (rinv known from last step)

            // ---- acc_j = sum_i q_i * E_ij ; 16 uniform b128 broadcasts ----
            const f32x4* qv = (const f32x4*)(&qraw[ph][0]);
            f32x2 acc[8];
#pragma unroll
            for (int c = 0; c < 8; ++c) acc[c] = (f32x2){0.0f, 0.0f};
#pragma unroll
            for (int r = 0; r < 16; ++r) {
                f32x4 q4 = qv[r];
                f32x2 qlo = (f32x2){q4.x, q4.y};
                f32x2 qhi = (f32x2){q4.z, q4.w};
                acc[(2 * r) & 7] = qlo * e2[2 * r] + acc[(2 * r) & 7];         // v_pk_fma
                acc[(2 * r + 1) & 7] = qhi * e2[2 * r + 1] + acc[(2 * r + 1) & 7];
            }
            f32x2 s01 = (acc[0] + acc[1]) + (acc[2] + acc[3]);
            f32x2 s23 = (acc[4] + acc[5]) + (acc[6] + acc[7]);
            f32x2 sall = s01 + s23;
            float acc_s = sall.x + sall.y;

            float qn = acc_s * efr;
            bool upd = (mk > 0.0f);
            q = upd ? qn : q;           // masked step: q unchanged
            qraw[ph ^ 1][j] = q;        // publish for next step (in-order DS)

            // ---- renormalizer bookkeeping (OFF the critical chain) ----
            ktot = upd ? (ktot + kcur) : ktot; // kcur was applied this step
            unsigned a0u = __builtin_amdgcn_readfirstlane(__float_as_uint(acc_s));
            int ke = (int)((a0u >> 23) & 0xffu) - 127; // floor exponent of acc[0] (>0)
            ke = (ke < -60) ? -60 : ((ke > 60) ? 60 : ke); // runaway guard
            float rnew = __uint_as_float((unsigned)(127 - ke) << 23); // exact 2^-ke
            rinv = upd ? rnew : rinv;
            kcur = upd ? ke : kcur;
        }
    }

    // ---- epilogue 1: logz = log(sum_j q_j * exp(tstop_j)) + C0 + ktot*ln2 ----
    float et = __expf(tstop); // tstop[STOP]=NEG -> 0; q[STOP]=0 anyway
    float pe = q * et;
#pragma unroll
    for (int w = 32; w >= 1; w >>= 1) pe += __shfl_xor(pe, w, 64);
    float logz = __logf(pe) + C0 + (float)ktot * 0.6931471805599453f;

    // ---- epilogue 2: true-path score; lanes parallel over time steps ----
    float psc = 0.0f, pms = 0.0f;
#pragma unroll
    for (int k = 0; k < 8; ++k) {
        int s = j + 64 * k;
        int tg = tags[s * BATCH + b];
        float mk = mreg[k]; // this lane's preloaded mask[s]
        int tprev = (s == 0) ? START_TAG : tags[(s - 1) * BATCH + b];
        float em = feats[((size_t)s * BATCH + b) * NTAG + tg];
        psc = fmaf(em + trans[tprev * NTAG + tg], mk, psc);
        pms += mk;
    }
#pragma unroll
    for (int w = 32; w >= 1; w >>= 1) {
        psc += __shfl_xor(psc, w, 64);
        pms += __shfl_xor(pms, w, 64);
    }

    if (j == 0) {
        int last_idx = (int)(pms + 0.5f) - 1;
        int ltag = tags[last_idx * BATCH + b];
        float score = psc + trans[ltag * NTAG + STOP_TAG];
        diff[b] = logz - score;
    }
}

__global__ __launch_bounds__(512) void crf_reduce(const float* __restrict__ diff,
                                                  float* __restrict__ out) {
    __shared__ float sdata[8];
    int t = threadIdx.x;
    float val = diff[t];
#pragma unroll
    for (int w = 32; w >= 1; w >>= 1)
        val += __shfl_xor(val, w, 64);
    if ((t & 63) == 0) sdata[t >> 6] = val;
    __syncthreads();
    if (t == 0) {
        float ssum = 0.0f;
        for (int i = 0; i < 8; ++i) ssum += sdata[i];
        out[0] = ssum * (1.0f / (float)BATCH);
    }
}

extern "C" void kernel_launch(void* const* d_in, const int* in_sizes, int n_in,
                              void* d_out, int out_size, void* d_ws, size_t ws_size,
                              hipStream_t stream) {
    const float* feats = (const float*)d_in[0];
    const int* tags = (const int*)d_in[1];
    const float* mask = (const float*)d_in[2];
    const float* trans = (const float*)d_in[3];
    float* out = (float*)d_out;
    float* diff = (float*)d_ws; // 512 floats

    crf_fwd<<<BATCH, 64, 0, stream>>>(feats, tags, mask, trans, diff);
    crf_reduce<<<1, 512, 0, stream>>>(diff, out);
}